// Round 3
// baseline (49620.132 us; speedup 1.0000x reference)
//
#include <hip/hip_runtime.h>
#include <cstdint>
#include <cstddef>

// Decoder (DA-RNN): B=512, T=256, E=D=256.
// Round 3: phase reorder (q+gates GEMVs first, 4 barriers/step), register
// prefetch of the Ph score stream (pbuf[32] half8, loaded one step ahead),
// paired-rcp score math (halves transcendental load), yh in LDS, fused preps.

typedef _Float16 half8 __attribute__((ext_vector_type(8)));
typedef _Float16 half4v __attribute__((ext_vector_type(4)));
typedef _Float16 half2v __attribute__((ext_vector_type(2)));

__device__ __forceinline__ float rcpf_(float x) { return __builtin_amdgcn_rcpf(x); }
__device__ __forceinline__ float sigmoidf_(float x) { return rcpf_(1.f + __expf(-x)); }
__device__ __forceinline__ float tanhf_(float x) { return 1.f - 2.f * rcpf_(1.f + __expf(2.f * x)); }

#if defined(__has_builtin)
#if __has_builtin(__builtin_amdgcn_fdot2)
#define HAS_FDOT2 1
#endif
#endif
#ifndef HAS_FDOT2
#define HAS_FDOT2 0
#endif

__device__ __forceinline__ float fdot2_(half2v a, half2v b, float c) {
#if HAS_FDOT2
  return __builtin_amdgcn_fdot2(a, b, c, false);
#else
  return fmaf((float)a[0], (float)b[0], fmaf((float)a[1], (float)b[1], c));
#endif
}

// ---------------- prep kernels ----------------

// wT[e*256+f] = attn_w1[f*768 + 512 + e]   (transposed w1_enc, fp32)
__global__ void k_prep_wT(const float* __restrict__ w1, float* __restrict__ wT) {
  int id = blockIdx.x * 256 + threadIdx.x;
  int e = id >> 8, f = id & 255;
  wT[id] = w1[f * 768 + 512 + e];
}

// w1hcP[(c*512 + e*2 + jh)*8 + m] = w1[e*768 + jh*256 + c*8 + m]  (fp16)
__global__ void k_prep_w1hcP(const float* __restrict__ w1, _Float16* __restrict__ o) {
  int id = blockIdx.x * 256 + threadIdx.x;  // 131072 total
  int m = id & 7, lane = (id >> 3) & 511, c = id >> 12;
  int e = lane >> 1, jh = lane & 1;
  o[id] = (_Float16)w1[e * 768 + jh * 256 + c * 8 + m];
}

// whhT3[(jp*1024 + k)*2 + r] = W_hh[k*256 + 2*jp + r]  (fp16, j-pair packed)
__global__ void k_prep_whhT3(const float* __restrict__ whh, _Float16* __restrict__ o) {
  int id = blockIdx.x * 256 + threadIdx.x;  // 262144 total
  int r = id & 1, k = (id >> 1) & 1023, jp = id >> 11;
  o[id] = (_Float16)whh[k * 256 + 2 * jp + r];
}

// Fused: enc_proj GEMM + bias -> P=exp(2*encp) fp16 [b][e/8][t][e%8];
// also xh (x as fp16, [b][t][e]) and xf[b*256+t] = x[b,t,:].fcw.
__global__ __launch_bounds__(256) void k_encp(const float* __restrict__ x,
                                              const float* __restrict__ wT,
                                              const float* __restrict__ b1,
                                              const float* __restrict__ fcw,
                                              _Float16* __restrict__ Ph2,
                                              _Float16* __restrict__ xh,
                                              float* __restrict__ xf) {
  __shared__ __align__(16) float xl[16][256];
  __shared__ float fw[256];
  __shared__ float part[16][17];
  const int tid = threadIdx.x;
  const int m0 = blockIdx.x * 16;
  fw[tid] = fcw[tid];
#pragma unroll
  for (int r = 0; r < 16; ++r) xl[r][tid] = x[(size_t)(m0 + r) * 256 + tid];
  __syncthreads();
  // xh
#pragma unroll
  for (int r = 0; r < 16; ++r) xh[(size_t)(m0 + r) * 256 + tid] = (_Float16)xl[r][tid];
  // xf partials
  {
    int r = tid >> 4, p = tid & 15;
    float s = 0.f;
#pragma unroll
    for (int u = 0; u < 16; ++u) s = fmaf(xl[r][p * 16 + u], fw[p * 16 + u], s);
    part[r][p] = s;
  }
  __syncthreads();
  if (tid < 16) {
    float t = 0.f;
#pragma unroll
    for (int p2 = 0; p2 < 16; ++p2) t += part[tid][p2];
    xf[m0 + tid] = t;
  }
  // GEMM
  float acc[16];
#pragma unroll
  for (int r = 0; r < 16; ++r) acc[r] = 0.f;
  for (int e = 0; e < 256; e += 4) {
    float w0 = wT[(e + 0) * 256 + tid];
    float w1_ = wT[(e + 1) * 256 + tid];
    float w2_ = wT[(e + 2) * 256 + tid];
    float w3_ = wT[(e + 3) * 256 + tid];
#pragma unroll
    for (int r = 0; r < 16; ++r) {
      float4 xv = *reinterpret_cast<const float4*>(&xl[r][e]);
      acc[r] = fmaf(xv.x, w0, acc[r]);
      acc[r] = fmaf(xv.y, w1_, acc[r]);
      acc[r] = fmaf(xv.z, w2_, acc[r]);
      acc[r] = fmaf(xv.w, w3_, acc[r]);
    }
  }
  float bb = b1[tid];
  const int e = tid;
#pragma unroll
  for (int r = 0; r < 16; ++r) {
    int m = m0 + r, b = m >> 8, t = m & 255;
    float p = __expf(2.f * (acc[r] + bb));
    Ph2[((size_t)(b * 32 + (e >> 3)) * 256 + t) * 8 + (e & 7)] = (_Float16)p;
  }
}

// ---------------- the scan ----------------
// grid 256 x 512 threads; wg owns 2 batch rows (g=0/1); 256 steps; 4 barriers.
__global__ __launch_bounds__(512, 2) void k_scan(
    const _Float16* __restrict__ Ph2, const _Float16* __restrict__ xh,
    const _Float16* __restrict__ w1hcP, const _Float16* __restrict__ whhT3,
    const float* __restrict__ xf, const float* __restrict__ y_hist,
    const float* __restrict__ w2g, const float* __restrict__ Wih,
    const float* __restrict__ bih, const float* __restrict__ bhh,
    const float* __restrict__ fcw, const float* __restrict__ fcb,
    const float* __restrict__ fcfw, const float* __restrict__ fcfb,
    float* __restrict__ out) {
  __shared__ __align__(16) float hc[2][512];        // fp32 [g][ h | c ]
  __shared__ __align__(16) _Float16 hcH[2][512];    // fp16 mirror
  __shared__ __align__(16) float qpart[2][2][256];  // [g][jh][e]
  __shared__ __align__(16) float Qs[2][256];        // exp(2q)
  __shared__ __align__(16) float ealpha[2][256];
  __shared__ __align__(16) float gpart[4][2][1024]; // [jq][g][k]
  __shared__ __align__(16) float cpart[2][8][256];  // final ctx only
  __shared__ __align__(16) float w2l[256];
  __shared__ __align__(16) float Wihl[1024];
  __shared__ __align__(16) float bl[1024];
  __shared__ __align__(16) float xfL[2][256];
  __shared__ __align__(16) float yhL[2][256];
  __shared__ float redA[8], redB[8];

  const int tid = threadIdx.x;
  const int g = tid >> 8;
  const int tt = tid & 255;
  const int wv = tid >> 6;
  const int lane = tid & 63;
  const int b0 = blockIdx.x * 2;

  // ---- init ----
  ((float*)hc)[tid] = 0.f;
  ((float*)hc)[tid + 512] = 0.f;
  {
    _Float16 z = (_Float16)0.f;
    ((_Float16*)hcH)[tid] = z;
    ((_Float16*)hcH)[tid + 512] = z;
  }
  if (g == 0) w2l[tt] = w2g[tt];
  Wihl[tid] = Wih[tid];
  Wihl[tid + 512] = Wih[tid + 512];
  bl[tid] = bih[tid] + bhh[tid];
  bl[tid + 512] = bih[tid + 512] + bhh[tid + 512];
  xfL[g][tt] = xf[(size_t)(b0 + g) * 256 + tt];
  yhL[g][tt] = y_hist[(size_t)(b0 + g) * 256 + tt];
  __syncthreads();
  float w2sum = 0.f;
  for (int e2 = 0; e2 < 256; ++e2) w2sum += w2l[e2];
  const float fcb0 = fcb[0];
  const float fcwy = fcw[256];

  // per-thread pointers
  const half8* wq = reinterpret_cast<const half8*>(w1hcP) + tid;  // chunk c: wq[c*512]
  const int jh = tid & 1;
  const int eQ = tid >> 1;
  const half8* prow = reinterpret_cast<const half8*>(Ph2) + ((size_t)(b0 + g) * 32) * 256 + tt;
  const int ks = tid & 127, jq = tid >> 7, k0 = (tid & 127) * 8;
  const half8* wgp = reinterpret_cast<const half8*>(whhT3) + ks * 2;

  float rs0 = 0.f;
  half8 pbuf[32];
#pragma unroll
  for (int c = 0; c < 32; ++c) pbuf[c] = __builtin_nontemporal_load(prow + c * 256);

#pragma unroll 1
  for (int s = 0; s < 256; ++s) {
    // ======== Phase A: q GEMV + gates GEMV (both only need hcH) ========
    float a0 = 0.f, a1 = 0.f;
    {
      const half2v* h0 = reinterpret_cast<const half2v*>(&hcH[0][jh * 256]);
      const half2v* h1 = reinterpret_cast<const half2v*>(&hcH[1][jh * 256]);
#pragma unroll 8
      for (int c = 0; c < 32; ++c) {
        half8 wv8 = wq[c * 512];
#pragma unroll
        for (int p = 0; p < 4; ++p) {
          half2v wp2 = __builtin_shufflevector(wv8, wv8, 0, 1);
          if (p == 1) wp2 = __builtin_shufflevector(wv8, wv8, 2, 3);
          if (p == 2) wp2 = __builtin_shufflevector(wv8, wv8, 4, 5);
          if (p == 3) wp2 = __builtin_shufflevector(wv8, wv8, 6, 7);
          a0 = fdot2_(wp2, h0[c * 4 + p], a0);
          a1 = fdot2_(wp2, h1[c * 4 + p], a1);
        }
      }
    }
    qpart[0][jh][eQ] = a0;
    qpart[1][jh][eQ] = a1;

    float acc0[8], acc1[8];
#pragma unroll
    for (int m = 0; m < 8; ++m) { acc0[m] = 0.f; acc1[m] = 0.f; }
    {
      const unsigned int* hu0 = reinterpret_cast<const unsigned int*>(&hcH[0][0]);
      const unsigned int* hu1 = reinterpret_cast<const unsigned int*>(&hcH[1][0]);
      const int jp0 = jq * 32;
#pragma unroll 4
      for (int u = 0; u < 32; ++u) {
        int jp = jp0 + u;
        half8 wa = wgp[jp * 256];
        half8 wb = wgp[jp * 256 + 1];
        half2v h0 = __builtin_bit_cast(half2v, hu0[jp]);
        half2v h1 = __builtin_bit_cast(half2v, hu1[jp]);
        half2v p0 = __builtin_shufflevector(wa, wa, 0, 1);
        half2v p1 = __builtin_shufflevector(wa, wa, 2, 3);
        half2v p2 = __builtin_shufflevector(wa, wa, 4, 5);
        half2v p3 = __builtin_shufflevector(wa, wa, 6, 7);
        half2v p4 = __builtin_shufflevector(wb, wb, 0, 1);
        half2v p5 = __builtin_shufflevector(wb, wb, 2, 3);
        half2v p6 = __builtin_shufflevector(wb, wb, 4, 5);
        half2v p7 = __builtin_shufflevector(wb, wb, 6, 7);
        acc0[0] = fdot2_(p0, h0, acc0[0]); acc1[0] = fdot2_(p0, h1, acc1[0]);
        acc0[1] = fdot2_(p1, h0, acc0[1]); acc1[1] = fdot2_(p1, h1, acc1[1]);
        acc0[2] = fdot2_(p2, h0, acc0[2]); acc1[2] = fdot2_(p2, h1, acc1[2]);
        acc0[3] = fdot2_(p3, h0, acc0[3]); acc1[3] = fdot2_(p3, h1, acc1[3]);
        acc0[4] = fdot2_(p4, h0, acc0[4]); acc1[4] = fdot2_(p4, h1, acc1[4]);
        acc0[5] = fdot2_(p5, h0, acc0[5]); acc1[5] = fdot2_(p5, h1, acc1[5]);
        acc0[6] = fdot2_(p6, h0, acc0[6]); acc1[6] = fdot2_(p6, h1, acc1[6]);
        acc0[7] = fdot2_(p7, h0, acc0[7]); acc1[7] = fdot2_(p7, h1, acc1[7]);
      }
    }
    *reinterpret_cast<float4*>(&gpart[jq][0][k0]) = *reinterpret_cast<float4*>(&acc0[0]);
    *reinterpret_cast<float4*>(&gpart[jq][0][k0 + 4]) = *reinterpret_cast<float4*>(&acc0[4]);
    *reinterpret_cast<float4*>(&gpart[jq][1][k0]) = *reinterpret_cast<float4*>(&acc1[0]);
    *reinterpret_cast<float4*>(&gpart[jq][1][k0 + 4]) = *reinterpret_cast<float4*>(&acc1[4]);
    __syncthreads();  // B1

    // ======== Phase B: Qs = exp(2q) ========
    Qs[g][tt] = __expf(2.f * (qpart[g][0][tt] + qpart[g][1][tt]));
    __syncthreads();  // B2

    // ======== Phase C: scores from registers, paired rcp ========
    float sacc = 0.f;
    {
      const float4* q4 = reinterpret_cast<const float4*>(&Qs[g][0]);
      const float4* w4 = reinterpret_cast<const float4*>(&w2l[0]);
#pragma unroll
      for (int c = 0; c < 32; ++c) {
        half8 pv = pbuf[c];
        float4 qa = q4[2 * c], qb = q4[2 * c + 1];
        float4 wa = w4[2 * c], wb = w4[2 * c + 1];
        float x0 = fmaf((float)pv[0], qa.x, 1.f);
        float x1 = fmaf((float)pv[1], qa.y, 1.f);
        float x2 = fmaf((float)pv[2], qa.z, 1.f);
        float x3 = fmaf((float)pv[3], qa.w, 1.f);
        float x4 = fmaf((float)pv[4], qb.x, 1.f);
        float x5 = fmaf((float)pv[5], qb.y, 1.f);
        float x6 = fmaf((float)pv[6], qb.z, 1.f);
        float x7 = fmaf((float)pv[7], qb.w, 1.f);
        sacc = fmaf(fmaf(wa.x, x1, wa.y * x0), rcpf_(x0 * x1), sacc);
        sacc = fmaf(fmaf(wa.z, x3, wa.w * x2), rcpf_(x2 * x3), sacc);
        sacc = fmaf(fmaf(wb.x, x5, wb.y * x4), rcpf_(x4 * x5), sacc);
        sacc = fmaf(fmaf(wb.z, x7, wb.w * x6), rcpf_(x6 * x7), sacc);
      }
    }
    // prefetch Ph for next step (overlaps softmax + pointwise + next GEMVs)
    if (s != 255) {
#pragma unroll
      for (int c = 0; c < 32; ++c) pbuf[c] = __builtin_nontemporal_load(prow + c * 256);
    }
    float sc = w2sum - 2.f * sacc;
    float ea = __expf(sc);  // |sc| <= ~30, fp32-safe
    ealpha[g][tt] = ea;
    float ef = ea * xfL[g][tt];
    float es = ea;
#pragma unroll
    for (int off = 32; off > 0; off >>= 1) {
      es += __shfl_xor(es, off);
      ef += __shfl_xor(ef, off);
    }
    if (lane == 0) { redA[wv] = es; redB[wv] = ef; }
    __syncthreads();  // B3

    // ======== Phase D: y_tilde + LSTM pointwise ========
    float es0 = redA[0] + redA[1] + redA[2] + redA[3];
    float es1 = redA[4] + redA[5] + redA[6] + redA[7];
    float ef0 = redB[0] + redB[1] + redB[2] + redB[3];
    float ef1 = redB[4] + redB[5] + redB[6] + redB[7];
    float yt0 = ef0 * rcpf_(es0) + fmaf(yhL[0][s], fcwy, fcb0);
    float yt1 = ef1 * rcpf_(es1) + fmaf(yhL[1][s], fcwy, fcb0);
    rs0 = rcpf_(g == 0 ? es0 : es1);
    {
      float yt = (g == 0) ? yt0 : yt1;
      float gi = fmaf(yt, Wihl[tt], bl[tt]);
      float gf = fmaf(yt, Wihl[256 + tt], bl[256 + tt]);
      float gc = fmaf(yt, Wihl[512 + tt], bl[512 + tt]);
      float go = fmaf(yt, Wihl[768 + tt], bl[768 + tt]);
#pragma unroll
      for (int q2 = 0; q2 < 4; ++q2) {
        gi += gpart[q2][g][tt];
        gf += gpart[q2][g][256 + tt];
        gc += gpart[q2][g][512 + tt];
        go += gpart[q2][g][768 + tt];
      }
      float iv = sigmoidf_(gi), fv = sigmoidf_(gf), gv = tanhf_(gc), ov = sigmoidf_(go);
      float cold = hc[g][256 + tt];
      float cn = fmaf(fv, cold, iv * gv);
      float hn = ov * tanhf_(cn);
      hc[g][tt] = hn;
      hc[g][256 + tt] = cn;
      hcH[g][tt] = (_Float16)hn;
      hcH[g][256 + tt] = (_Float16)cn;
    }
    __syncthreads();  // B4
  }

  // ---- final context (ealpha/rs0 from step 255) ----
  const int t8 = tt >> 5, l5 = tt & 31;
  {
    const half8* xrow = reinterpret_cast<const half8*>(xh + ((size_t)(b0 + g) * 256 + t8 * 32) * 256);
    float ac[8];
#pragma unroll
    for (int m = 0; m < 8; ++m) ac[m] = 0.f;
#pragma unroll 4
    for (int it = 0; it < 32; ++it) {
      float al = ealpha[g][t8 * 32 + it];
      half8 xv = xrow[it * 32 + l5];
#pragma unroll
      for (int m = 0; m < 8; ++m) ac[m] = fmaf(al, (float)xv[m], ac[m]);
    }
    *reinterpret_cast<float4*>(&cpart[g][t8][l5 * 8]) = *reinterpret_cast<float4*>(&ac[0]);
    *reinterpret_cast<float4*>(&cpart[g][t8][l5 * 8 + 4]) = *reinterpret_cast<float4*>(&ac[4]);
  }
  __syncthreads();
  float cv = 0.f;
#pragma unroll
  for (int u = 0; u < 8; ++u) cv += cpart[g][u][tt];
  cv *= rs0;

  // ---- epilogue ----
  {
    float hval = hc[g][tt];
    float p0 = hval * fcfw[tt] + cv * fcfw[256 + tt];
    float p1 = hval * fcfw[512 + tt] + cv * fcfw[768 + tt];
#pragma unroll
    for (int off = 32; off > 0; off >>= 1) {
      p0 += __shfl_xor(p0, off);
      p1 += __shfl_xor(p1, off);
    }
    __syncthreads();
    if (lane == 0) { redA[wv] = p0; redB[wv] = p1; }
    __syncthreads();
    if (tid < 4) {
      int g2 = tid >> 1, o = tid & 1;
      const float* r = (o == 0) ? redA : redB;
      float v = fcfb[o] + r[g2 * 4 + 0] + r[g2 * 4 + 1] + r[g2 * 4 + 2] + r[g2 * 4 + 3];
      out[(b0 + g2) * 2 + o] = v;
    }
  }
}

extern "C" void kernel_launch(void* const* d_in, const int* in_sizes, int n_in,
                              void* d_out, int out_size, void* d_ws, size_t ws_size,
                              hipStream_t stream) {
  (void)in_sizes; (void)n_in; (void)out_size; (void)ws_size;
  const float* x    = (const float*)d_in[0];
  const float* yh   = (const float*)d_in[1];
  const float* w1   = (const float*)d_in[2];
  const float* b1   = (const float*)d_in[3];
  const float* w2   = (const float*)d_in[4];
  /* d_in[5] attn_b2: softmax-invariant, unused */
  const float* Wih  = (const float*)d_in[6];
  const float* Whh  = (const float*)d_in[7];
  const float* bih  = (const float*)d_in[8];
  const float* bhh  = (const float*)d_in[9];
  const float* fcw  = (const float*)d_in[10];
  const float* fcb  = (const float*)d_in[11];
  const float* fcfw = (const float*)d_in[12];
  const float* fcfb = (const float*)d_in[13];
  float* out = (float*)d_out;

  char* ws = (char*)d_ws;
  _Float16* Ph2   = (_Float16*)(ws);                      // 67108864 B
  _Float16* xh    = (_Float16*)(ws + (size_t)67108864);   // 67108864 B
  float*    wT    = (float*)   (ws + (size_t)134217728);  // 262144 B
  _Float16* w1hcP = (_Float16*)(ws + (size_t)134479872);  // 262144 B
  _Float16* whhT3 = (_Float16*)(ws + (size_t)134742016);  // 524288 B
  float*    xf    = (float*)   (ws + (size_t)135266304);  // 524288 B
  // total: 135790592 B (~129.5 MB)

  k_prep_wT   <<<256,  256, 0, stream>>>(w1, wT);
  k_prep_w1hcP<<<512,  256, 0, stream>>>(w1, w1hcP);
  k_prep_whhT3<<<1024, 256, 0, stream>>>(Whh, whhT3);
  k_encp      <<<8192, 256, 0, stream>>>(x, wT, b1, fcw, Ph2, xh, xf);
  k_scan      <<<256,  512, 0, stream>>>(Ph2, xh, w1hcP, whhT3, xf, yh, w2, Wih,
                                         bih, bhh, fcw, fcb, fcfw, fcfb, out);
}

// Round 4
// 8949.045 us; speedup vs baseline: 5.5447x; 5.5447x over previous
//
#include <hip/hip_runtime.h>
#include <cstdint>
#include <cstddef>

// Decoder (DA-RNN): B=512, T=256, E=D=256.
// Round 4: Ph is STEP-INVARIANT -> load once into 32 named half8 registers
// (no array => no scratch demotion), score phase runs from registers.
// 3 barriers/step (shfl_xor q-combine). Conflict-free gpart layout.
// Plain cached loads (nt removed). Weights re-stream from L2 each step.

typedef _Float16 half8 __attribute__((ext_vector_type(8)));
typedef _Float16 half4v __attribute__((ext_vector_type(4)));
typedef _Float16 half2v __attribute__((ext_vector_type(2)));

__device__ __forceinline__ float rcpf_(float x) { return __builtin_amdgcn_rcpf(x); }
__device__ __forceinline__ float sigmoidf_(float x) { return rcpf_(1.f + __expf(-x)); }
__device__ __forceinline__ float tanhf_(float x) { return 1.f - 2.f * rcpf_(1.f + __expf(2.f * x)); }

#if defined(__has_builtin)
#if __has_builtin(__builtin_amdgcn_fdot2)
#define HAS_FDOT2 1
#endif
#endif
#ifndef HAS_FDOT2
#define HAS_FDOT2 0
#endif

__device__ __forceinline__ float fdot2_(half2v a, half2v b, float c) {
#if HAS_FDOT2
  return __builtin_amdgcn_fdot2(a, b, c, false);
#else
  return fmaf((float)a[0], (float)b[0], fmaf((float)a[1], (float)b[1], c));
#endif
}

// ---------------- prep kernels ----------------

// wT[e*256+f] = attn_w1[f*768 + 512 + e]   (transposed w1_enc, fp32)
__global__ void k_prep_wT(const float* __restrict__ w1, float* __restrict__ wT) {
  int id = blockIdx.x * 256 + threadIdx.x;
  int e = id >> 8, f = id & 255;
  wT[id] = w1[f * 768 + 512 + e];
}

// w1hcP[(c*512 + e*2 + jh)*8 + m] = w1[e*768 + jh*256 + c*8 + m]  (fp16)
__global__ void k_prep_w1hcP(const float* __restrict__ w1, _Float16* __restrict__ o) {
  int id = blockIdx.x * 256 + threadIdx.x;  // 131072 total
  int m = id & 7, lane = (id >> 3) & 511, c = id >> 12;
  int e = lane >> 1, jh = lane & 1;
  o[id] = (_Float16)w1[e * 768 + jh * 256 + c * 8 + m];
}

// whhT3[(jp*1024 + k)*2 + r] = W_hh[k*256 + 2*jp + r]  (fp16, j-pair packed)
__global__ void k_prep_whhT3(const float* __restrict__ whh, _Float16* __restrict__ o) {
  int id = blockIdx.x * 256 + threadIdx.x;  // 262144 total
  int r = id & 1, k = (id >> 1) & 1023, jp = id >> 11;
  o[id] = (_Float16)whh[k * 256 + 2 * jp + r];
}

// Fused: enc_proj GEMM + bias -> P=exp(2*encp) fp16 [b][e/8][t][e%8];
// also xh (x fp16 [b][t][e]) and xf[b*256+t] = x[b,t,:].fcw.
__global__ __launch_bounds__(256) void k_encp(const float* __restrict__ x,
                                              const float* __restrict__ wT,
                                              const float* __restrict__ b1,
                                              const float* __restrict__ fcw,
                                              _Float16* __restrict__ Ph2,
                                              _Float16* __restrict__ xh,
                                              float* __restrict__ xf) {
  __shared__ __align__(16) float xl[16][256];
  __shared__ float fw[256];
  __shared__ float part[16][17];
  const int tid = threadIdx.x;
  const int m0 = blockIdx.x * 16;
  fw[tid] = fcw[tid];
#pragma unroll
  for (int r = 0; r < 16; ++r) xl[r][tid] = x[(size_t)(m0 + r) * 256 + tid];
  __syncthreads();
#pragma unroll
  for (int r = 0; r < 16; ++r) xh[(size_t)(m0 + r) * 256 + tid] = (_Float16)xl[r][tid];
  {
    int r = tid >> 4, p = tid & 15;
    float s = 0.f;
#pragma unroll
    for (int u = 0; u < 16; ++u) s = fmaf(xl[r][p * 16 + u], fw[p * 16 + u], s);
    part[r][p] = s;
  }
  __syncthreads();
  if (tid < 16) {
    float t = 0.f;
#pragma unroll
    for (int p2 = 0; p2 < 16; ++p2) t += part[tid][p2];
    xf[m0 + tid] = t;
  }
  float acc[16];
#pragma unroll
  for (int r = 0; r < 16; ++r) acc[r] = 0.f;
  for (int e = 0; e < 256; e += 4) {
    float w0 = wT[(e + 0) * 256 + tid];
    float w1_ = wT[(e + 1) * 256 + tid];
    float w2_ = wT[(e + 2) * 256 + tid];
    float w3_ = wT[(e + 3) * 256 + tid];
#pragma unroll
    for (int r = 0; r < 16; ++r) {
      float4 xv = *reinterpret_cast<const float4*>(&xl[r][e]);
      acc[r] = fmaf(xv.x, w0, acc[r]);
      acc[r] = fmaf(xv.y, w1_, acc[r]);
      acc[r] = fmaf(xv.z, w2_, acc[r]);
      acc[r] = fmaf(xv.w, w3_, acc[r]);
    }
  }
  float bb = b1[tid];
  const int e = tid;
#pragma unroll
  for (int r = 0; r < 16; ++r) {
    int m = m0 + r, b = m >> 8, t = m & 255;
    float p = __expf(2.f * (acc[r] + bb));
    Ph2[((size_t)(b * 32 + (e >> 3)) * 256 + t) * 8 + (e & 7)] = (_Float16)p;
  }
}

// ---------------- the scan ----------------
// grid 256 x 512 threads; wg owns 2 batch rows (g=0/1); 256 steps; 3 barriers.
__global__ __launch_bounds__(512, 2) void k_scan(
    const _Float16* __restrict__ Ph2, const _Float16* __restrict__ xh,
    const _Float16* __restrict__ w1hcP, const _Float16* __restrict__ whhT3,
    const float* __restrict__ xf, const float* __restrict__ y_hist,
    const float* __restrict__ w2g, const float* __restrict__ Wih,
    const float* __restrict__ bih, const float* __restrict__ bhh,
    const float* __restrict__ fcw, const float* __restrict__ fcb,
    const float* __restrict__ fcfw, const float* __restrict__ fcfb,
    float* __restrict__ out) {
  __shared__ __align__(16) float hc[2][512];         // fp32 [g][ h | c ]
  __shared__ __align__(16) _Float16 hcH[2][512];     // fp16 mirror
  __shared__ __align__(16) float Qs[2][256];         // exp(2q)
  __shared__ __align__(16) float ealpha[2][256];
  __shared__ float gpart[4][2][8][129];              // [jq][g][m][ks] conflict-free
  __shared__ __align__(16) float cpart[2][8][256];   // final ctx only
  __shared__ __align__(16) float w2l[256];
  __shared__ __align__(16) float Wihl[1024];
  __shared__ __align__(16) float bl[1024];
  __shared__ __align__(16) float xfL[2][256];
  __shared__ __align__(16) float yhL[2][256];
  __shared__ float redA[8], redB[8];

  const int tid = threadIdx.x;
  const int g = tid >> 8;
  const int tt = tid & 255;
  const int wv = tid >> 6;
  const int lane = tid & 63;
  const int b0 = blockIdx.x * 2;

  // ---- init ----
  ((float*)hc)[tid] = 0.f;
  ((float*)hc)[tid + 512] = 0.f;
  {
    _Float16 z = (_Float16)0.f;
    ((_Float16*)hcH)[tid] = z;
    ((_Float16*)hcH)[tid + 512] = z;
  }
  if (g == 0) w2l[tt] = w2g[tt];
  Wihl[tid] = Wih[tid];
  Wihl[tid + 512] = Wih[tid + 512];
  bl[tid] = bih[tid] + bhh[tid];
  bl[tid + 512] = bih[tid + 512] + bhh[tid + 512];
  xfL[g][tt] = xf[(size_t)(b0 + g) * 256 + tt];
  yhL[g][tt] = y_hist[(size_t)(b0 + g) * 256 + tt];
  __syncthreads();
  float w2sum = 0.f;
  for (int e2 = 0; e2 < 256; ++e2) w2sum += w2l[e2];
  const float fcb0 = fcb[0];
  const float fcwy = fcw[256];

  // per-thread pointers
  const half8* wq = reinterpret_cast<const half8*>(w1hcP) + tid;  // chunk c: wq[c*512]
  const int jh = tid & 1;
  const int eQ = tid >> 1;
  const half8* prow = reinterpret_cast<const half8*>(Ph2) + ((size_t)(b0 + g) * 32) * 256 + tt;
  const int ks = tid & 127, jq = tid >> 7;
  const half8* wgp = reinterpret_cast<const half8*>(whhT3) + ks * 2;
  const int mR = tt & 7, kR = tt >> 3;

  // ---- Ph resident in registers: 32 NAMED half8 (128 VGPRs), step-invariant ----
#define LDP(N) half8 p##N = prow[(N) * 256]
  LDP(0); LDP(1); LDP(2); LDP(3); LDP(4); LDP(5); LDP(6); LDP(7);
  LDP(8); LDP(9); LDP(10); LDP(11); LDP(12); LDP(13); LDP(14); LDP(15);
  LDP(16); LDP(17); LDP(18); LDP(19); LDP(20); LDP(21); LDP(22); LDP(23);
  LDP(24); LDP(25); LDP(26); LDP(27); LDP(28); LDP(29); LDP(30); LDP(31);
#undef LDP

  float rs0 = 0.f;

#pragma unroll 1
  for (int s = 0; s < 256; ++s) {
    // ======== Phase A: q GEMV (+shfl combine -> Qs) and gates GEMV ========
    float a0 = 0.f, a1 = 0.f;
    {
      const half2v* h0 = reinterpret_cast<const half2v*>(&hcH[0][jh * 256]);
      const half2v* h1 = reinterpret_cast<const half2v*>(&hcH[1][jh * 256]);
#pragma unroll 8
      for (int c = 0; c < 32; ++c) {
        half8 wv8 = wq[c * 512];
#pragma unroll
        for (int p = 0; p < 4; ++p) {
          half2v wp2 = __builtin_shufflevector(wv8, wv8, 0, 1);
          if (p == 1) wp2 = __builtin_shufflevector(wv8, wv8, 2, 3);
          if (p == 2) wp2 = __builtin_shufflevector(wv8, wv8, 4, 5);
          if (p == 3) wp2 = __builtin_shufflevector(wv8, wv8, 6, 7);
          a0 = fdot2_(wp2, h0[c * 4 + p], a0);
          a1 = fdot2_(wp2, h1[c * 4 + p], a1);
        }
      }
    }
    a0 += __shfl_xor(a0, 1);
    a1 += __shfl_xor(a1, 1);
    Qs[jh][eQ] = __expf(2.f * (jh == 0 ? a0 : a1));

    float acc0[8], acc1[8];
#pragma unroll
    for (int m = 0; m < 8; ++m) { acc0[m] = 0.f; acc1[m] = 0.f; }
    {
      const unsigned int* hu0 = reinterpret_cast<const unsigned int*>(&hcH[0][0]);
      const unsigned int* hu1 = reinterpret_cast<const unsigned int*>(&hcH[1][0]);
      const int jp0 = jq * 32;
#pragma unroll 4
      for (int u = 0; u < 32; ++u) {
        int jp = jp0 + u;
        half8 wa = wgp[jp * 256];
        half8 wb = wgp[jp * 256 + 1];
        half2v h0 = __builtin_bit_cast(half2v, hu0[jp]);
        half2v h1 = __builtin_bit_cast(half2v, hu1[jp]);
        half2v q0 = __builtin_shufflevector(wa, wa, 0, 1);
        half2v q1 = __builtin_shufflevector(wa, wa, 2, 3);
        half2v q2 = __builtin_shufflevector(wa, wa, 4, 5);
        half2v q3 = __builtin_shufflevector(wa, wa, 6, 7);
        half2v q4_ = __builtin_shufflevector(wb, wb, 0, 1);
        half2v q5 = __builtin_shufflevector(wb, wb, 2, 3);
        half2v q6 = __builtin_shufflevector(wb, wb, 4, 5);
        half2v q7 = __builtin_shufflevector(wb, wb, 6, 7);
        acc0[0] = fdot2_(q0, h0, acc0[0]); acc1[0] = fdot2_(q0, h1, acc1[0]);
        acc0[1] = fdot2_(q1, h0, acc0[1]); acc1[1] = fdot2_(q1, h1, acc1[1]);
        acc0[2] = fdot2_(q2, h0, acc0[2]); acc1[2] = fdot2_(q2, h1, acc1[2]);
        acc0[3] = fdot2_(q3, h0, acc0[3]); acc1[3] = fdot2_(q3, h1, acc1[3]);
        acc0[4] = fdot2_(q4_, h0, acc0[4]); acc1[4] = fdot2_(q4_, h1, acc1[4]);
        acc0[5] = fdot2_(q5, h0, acc0[5]); acc1[5] = fdot2_(q5, h1, acc1[5]);
        acc0[6] = fdot2_(q6, h0, acc0[6]); acc1[6] = fdot2_(q6, h1, acc1[6]);
        acc0[7] = fdot2_(q7, h0, acc0[7]); acc1[7] = fdot2_(q7, h1, acc1[7]);
      }
    }
#pragma unroll
    for (int m = 0; m < 8; ++m) {
      gpart[jq][0][m][ks] = acc0[m];
      gpart[jq][1][m][ks] = acc1[m];
    }
    __syncthreads();  // B1

    // ======== Score phase: all from registers + LDS broadcast ========
    float sacc = 0.f;
    {
      const float4* q4 = reinterpret_cast<const float4*>(&Qs[g][0]);
      const float4* w4 = reinterpret_cast<const float4*>(&w2l[0]);
#define SCCHUNK(C, PV)                                                   \
      {                                                                  \
        float4 qa = q4[2 * (C)], qb = q4[2 * (C) + 1];                   \
        float4 wa = w4[2 * (C)], wb = w4[2 * (C) + 1];                   \
        float x0 = fmaf((float)PV[0], qa.x, 1.f);                        \
        float x1 = fmaf((float)PV[1], qa.y, 1.f);                        \
        float x2 = fmaf((float)PV[2], qa.z, 1.f);                        \
        float x3 = fmaf((float)PV[3], qa.w, 1.f);                        \
        float x4 = fmaf((float)PV[4], qb.x, 1.f);                        \
        float x5 = fmaf((float)PV[5], qb.y, 1.f);                        \
        float x6 = fmaf((float)PV[6], qb.z, 1.f);                        \
        float x7 = fmaf((float)PV[7], qb.w, 1.f);                        \
        sacc = fmaf(fmaf(wa.x, x1, wa.y * x0), rcpf_(x0 * x1), sacc);    \
        sacc = fmaf(fmaf(wa.z, x3, wa.w * x2), rcpf_(x2 * x3), sacc);    \
        sacc = fmaf(fmaf(wb.x, x5, wb.y * x4), rcpf_(x4 * x5), sacc);    \
        sacc = fmaf(fmaf(wb.z, x7, wb.w * x6), rcpf_(x6 * x7), sacc);    \
      }
      SCCHUNK(0, p0) SCCHUNK(1, p1) SCCHUNK(2, p2) SCCHUNK(3, p3)
      SCCHUNK(4, p4) SCCHUNK(5, p5) SCCHUNK(6, p6) SCCHUNK(7, p7)
      SCCHUNK(8, p8) SCCHUNK(9, p9) SCCHUNK(10, p10) SCCHUNK(11, p11)
      SCCHUNK(12, p12) SCCHUNK(13, p13) SCCHUNK(14, p14) SCCHUNK(15, p15)
      SCCHUNK(16, p16) SCCHUNK(17, p17) SCCHUNK(18, p18) SCCHUNK(19, p19)
      SCCHUNK(20, p20) SCCHUNK(21, p21) SCCHUNK(22, p22) SCCHUNK(23, p23)
      SCCHUNK(24, p24) SCCHUNK(25, p25) SCCHUNK(26, p26) SCCHUNK(27, p27)
      SCCHUNK(28, p28) SCCHUNK(29, p29) SCCHUNK(30, p30) SCCHUNK(31, p31)
#undef SCCHUNK
    }
    float sc = w2sum - 2.f * sacc;
    float ea = __expf(sc);  // |sc| bounded ~30, fp32-safe
    ealpha[g][tt] = ea;
    float ef = ea * xfL[g][tt];
    float es = ea;
#pragma unroll
    for (int off = 32; off > 0; off >>= 1) {
      es += __shfl_xor(es, off);
      ef += __shfl_xor(ef, off);
    }
    if (lane == 0) { redA[wv] = es; redB[wv] = ef; }
    __syncthreads();  // B2

    // ======== Phase D: y_tilde + gates sum + LSTM pointwise ========
    float es0 = redA[0] + redA[1] + redA[2] + redA[3];
    float es1 = redA[4] + redA[5] + redA[6] + redA[7];
    float ef0 = redB[0] + redB[1] + redB[2] + redB[3];
    float ef1 = redB[4] + redB[5] + redB[6] + redB[7];
    float yt0 = ef0 * rcpf_(es0) + fmaf(yhL[0][s], fcwy, fcb0);
    float yt1 = ef1 * rcpf_(es1) + fmaf(yhL[1][s], fcwy, fcb0);
    rs0 = rcpf_(g == 0 ? es0 : es1);
    {
      float yt = (g == 0) ? yt0 : yt1;
      float gi = fmaf(yt, Wihl[tt], bl[tt]);
      float gf = fmaf(yt, Wihl[256 + tt], bl[256 + tt]);
      float gc = fmaf(yt, Wihl[512 + tt], bl[512 + tt]);
      float go = fmaf(yt, Wihl[768 + tt], bl[768 + tt]);
#pragma unroll
      for (int q2 = 0; q2 < 4; ++q2) {
        gi += gpart[q2][g][mR][kR];
        gf += gpart[q2][g][mR][32 + kR];
        gc += gpart[q2][g][mR][64 + kR];
        go += gpart[q2][g][mR][96 + kR];
      }
      float iv = sigmoidf_(gi), fv = sigmoidf_(gf), gv = tanhf_(gc), ov = sigmoidf_(go);
      float cold = hc[g][256 + tt];
      float cn = fmaf(fv, cold, iv * gv);
      float hn = ov * tanhf_(cn);
      hc[g][tt] = hn;
      hc[g][256 + tt] = cn;
      hcH[g][tt] = (_Float16)hn;
      hcH[g][256 + tt] = (_Float16)cn;
    }
    __syncthreads();  // B3
  }

  // ---- final context (ealpha/rs0 from step 255) ----
  const int t8 = tt >> 5, l5 = tt & 31;
  {
    const half8* xrow = reinterpret_cast<const half8*>(xh + ((size_t)(b0 + g) * 256 + t8 * 32) * 256);
    float ac[8];
#pragma unroll
    for (int m = 0; m < 8; ++m) ac[m] = 0.f;
#pragma unroll 4
    for (int it = 0; it < 32; ++it) {
      float al = ealpha[g][t8 * 32 + it];
      half8 xv = xrow[it * 32 + l5];
#pragma unroll
      for (int m = 0; m < 8; ++m) ac[m] = fmaf(al, (float)xv[m], ac[m]);
    }
    *reinterpret_cast<float4*>(&cpart[g][t8][l5 * 8]) = *reinterpret_cast<float4*>(&ac[0]);
    *reinterpret_cast<float4*>(&cpart[g][t8][l5 * 8 + 4]) = *reinterpret_cast<float4*>(&ac[4]);
  }
  __syncthreads();
  float cv = 0.f;
#pragma unroll
  for (int u = 0; u < 8; ++u) cv += cpart[g][u][tt];
  cv *= rs0;

  // ---- epilogue ----
  {
    float hval = hc[g][tt];
    float o0 = hval * fcfw[tt] + cv * fcfw[256 + tt];
    float o1 = hval * fcfw[512 + tt] + cv * fcfw[768 + tt];
#pragma unroll
    for (int off = 32; off > 0; off >>= 1) {
      o0 += __shfl_xor(o0, off);
      o1 += __shfl_xor(o1, off);
    }
    __syncthreads();
    if (lane == 0) { redA[wv] = o0; redB[wv] = o1; }
    __syncthreads();
    if (tid < 4) {
      int g2 = tid >> 1, o = tid & 1;
      const float* r = (o == 0) ? redA : redB;
      float v = fcfb[o] + r[g2 * 4 + 0] + r[g2 * 4 + 1] + r[g2 * 4 + 2] + r[g2 * 4 + 3];
      out[(b0 + g2) * 2 + o] = v;
    }
  }
}

extern "C" void kernel_launch(void* const* d_in, const int* in_sizes, int n_in,
                              void* d_out, int out_size, void* d_ws, size_t ws_size,
                              hipStream_t stream) {
  (void)in_sizes; (void)n_in; (void)out_size; (void)ws_size;
  const float* x    = (const float*)d_in[0];
  const float* yh   = (const float*)d_in[1];
  const float* w1   = (const float*)d_in[2];
  const float* b1   = (const float*)d_in[3];
  const float* w2   = (const float*)d_in[4];
  /* d_in[5] attn_b2: softmax-invariant, unused */
  const float* Wih  = (const float*)d_in[6];
  const float* Whh  = (const float*)d_in[7];
  const float* bih  = (const float*)d_in[8];
  const float* bhh  = (const float*)d_in[9];
  const float* fcw  = (const float*)d_in[10];
  const float* fcb  = (const float*)d_in[11];
  const float* fcfw = (const float*)d_in[12];
  const float* fcfb = (const float*)d_in[13];
  float* out = (float*)d_out;

  char* ws = (char*)d_ws;
  _Float16* Ph2   = (_Float16*)(ws);                      // 67108864 B
  _Float16* xh    = (_Float16*)(ws + (size_t)67108864);   // 67108864 B
  float*    wT    = (float*)   (ws + (size_t)134217728);  // 262144 B
  _Float16* w1hcP = (_Float16*)(ws + (size_t)134479872);  // 262144 B
  _Float16* whhT3 = (_Float16*)(ws + (size_t)134742016);  // 524288 B
  float*    xf    = (float*)   (ws + (size_t)135266304);  // 524288 B
  // total: 135790592 B (~129.5 MB)

  k_prep_wT   <<<256,  256, 0, stream>>>(w1, wT);
  k_prep_w1hcP<<<512,  256, 0, stream>>>(w1, w1hcP);
  k_prep_whhT3<<<1024, 256, 0, stream>>>(Whh, whhT3);
  k_encp      <<<8192, 256, 0, stream>>>(x, wT, b1, fcw, Ph2, xh, xf);
  k_scan      <<<256,  512, 0, stream>>>(Ph2, xh, w1hcP, whhT3, xf, yh, w2, Wih,
                                         bih, bhh, fcw, fcb, fcfw, fcfb, out);
}